// Round 3
// baseline (283.716 us; speedup 1.0000x reference)
//
#include <hip/hip_runtime.h>

// B=8, L=128, R=2048, E=32, F=64
#define NB 8
#define NL 128
#define NR 2048
#define NE 32
#define NF 64
#define RT 64                 // r-rows per block
#define NRT (NR / RT)         // 32 r-tiles
#define EH 4                  // e-groups (blocks) per (b, rt)
#define EPB (NE / EH)         // 8 e's per block
#define NTHREADS 256
#define NWAVES (NTHREADS / 64)   // 4
#define AJ 8                  // A 16B-loads per thread per e (128 rows)
#define BJ 4                  // B 16B-loads per thread per e (64 rows)

typedef __attribute__((ext_vector_type(4)))  float f32x4;
typedef __attribute__((ext_vector_type(16))) float f32x16;
typedef __attribute__((ext_vector_type(8)))  short s16x8;
typedef __attribute__((ext_vector_type(2)))  unsigned int u32x2;

// (bf16(b) << 16) | bf16(a), round-half-up: +0x8000 then byte-select
__device__ __forceinline__ unsigned bf16pair(float a, float b) {
    union { float f; unsigned u; } ua, ub; ua.f = a; ub.f = b;
    return __builtin_amdgcn_perm(ub.u + 0x8000u, ua.u + 0x8000u, 0x07060302u);
}

__device__ __forceinline__ u32x2 pack4(f32x4 v) {
    u32x2 r;
    r.x = bf16pair(v.x, v.y);
    r.y = bf16pair(v.z, v.w);
    return r;
}

// Load the compiler cannot sink or track: issues exactly where placed,
// invisible to the compiler's vmcnt model (so its barriers don't drain it).
__device__ __forceinline__ void async_load4(f32x4& r, const float* p) {
    asm volatile("global_load_dwordx4 %0, %1, off" : "=v"(r) : "v"(p) : "memory");
}

// Tie the staging registers to a counted wait so dependent packs can't hoist.
#define TIE "+v"(tA[0]), "+v"(tA[1]), "+v"(tA[2]), "+v"(tA[3]), \
            "+v"(tA[4]), "+v"(tA[5]), "+v"(tA[6]), "+v"(tA[7]), \
            "+v"(tB[0]), "+v"(tB[1]), "+v"(tB[2]), "+v"(tB[3])

// 3 blocks/CU: LDS 50.3 KB x3 = 151 KB <= 160; VGPR cap 168 (est. ~150, no spill).
__global__ __launch_bounds__(NTHREADS, 3) void ff_kernel(
    const float* __restrict__ lig_feat,
    const float* __restrict__ rec_feat,
    const float* __restrict__ lig_coord,
    const float* __restrict__ rec_coord,
    float* __restrict__ out)
{
    // bf16 tiles; rows of 64 elems = 8 x 16B chunks, chunk XOR-swizzled by (row&7)
    __shared__ __align__(16) unsigned short sA[2][NL * NF];  // 2 x 16 KB
    __shared__ __align__(16) unsigned short sB[2][RT * NF];  // 2 x 8 KB
    __shared__ float sLc[3][NL];
    __shared__ float sRc[3][RT];
    __shared__ float sRed[NWAVES];

    const int blk = blockIdx.x;
    const int eh  = blk & (EH - 1);
    const int rt  = (blk >> 2) & (NRT - 1);
    const int b   = blk >> 7;            // 8*32*4 = 1024 blocks
    const int e0  = eh * EPB;
    const int r0  = rt * RT;
    const int t   = threadIdx.x;
    const int lane = t & 63;
    const int wv   = t >> 6;

    // per-thread load pattern: f4 = 16B column (const), rows row00 + 16*j
    const int f4    = t & 15;
    const int row00 = t >> 4;            // 0..15

    // ---- coords to LDS (compiler-tracked vmem, drained before asm loads) ----
    for (int i = t; i < 3 * NL; i += NTHREADS) {
        const int c = i >> 7, l = i & 127;
        sLc[c][l] = lig_coord[((long)b * NL + l) * 3 + c];
    }
    for (int i = t; i < 3 * RT; i += NTHREADS) {
        const int c = i >> 6, r = i & 63;
        sRc[c][r] = rec_coord[((long)b * NR + r0 + r) * 3 + c];
    }

    // ---- persistent streaming pointers; advance one e-slice per issue ----
    const float* pa[AJ];
    const float* pb[BJ];
    #pragma unroll
    for (int j = 0; j < AJ; ++j)
        pa[j] = lig_feat + (((long)b * NL + (row00 + 16 * j)) * NE + e0) * NF + f4 * 4;
    #pragma unroll
    for (int j = 0; j < BJ; ++j)
        pb[j] = rec_feat + (((long)b * NR + r0 + (row00 + 16 * j)) * NE + e0) * NF + f4 * 4;

    f32x4 tA[AJ], tB[BJ];

    // issue e0 (12 loads in flight across the distance phase)
    #pragma unroll
    for (int j = 0; j < AJ; ++j) { async_load4(tA[j], pa[j]); pa[j] += NF; }
    #pragma unroll
    for (int j = 0; j < BJ; ++j) { async_load4(tB[j], pb[j]); pb[j] += NF; }

    __syncthreads();   // coords visible (lgkm drain only; asm loads stay in flight)

    // ---- distances once, kept in registers (2 L-tiles: tl0, tl0+2) ----
    const int n  = lane & 31;
    const int h  = lane >> 5;
    const int tr  = wv & 1;              // 0..1 over RT/32
    const int tl0 = wv >> 1;             // 0..1; L-tiles tl0 and tl0+2
    const int colr = tr * 32 + n;
    const float rx = sRc[0][colr], ry = sRc[1][colr], rz = sRc[2][colr];
    float d[2][16];
    #pragma unroll
    for (int t2 = 0; t2 < 2; ++t2) {
        const int tl = tl0 + 2 * t2;
        #pragma unroll
        for (int i = 0; i < 16; ++i) {
            const int row = tl * 32 + 4 * h + (i & 3) + ((i >> 2) << 3);
            const float dx = sLc[0][row] - rx;
            const float dy = sLc[1][row] - ry;
            const float dz = sLc[2][row] - rz;
            d[t2][i] = sqrtf(dx * dx + dy * dy + dz * dz);
        }
    }

    // ---- wait e0 -> pack to buf0; issue e1; barrier ----
    asm volatile("s_waitcnt vmcnt(0)" : TIE :: "memory");
    #pragma unroll
    for (int j = 0; j < AJ; ++j) {
        const int r = row00 + 16 * j;
        const int pos = (((f4 >> 1) ^ (r & 7)) << 3) + ((f4 & 1) << 2);
        *(u32x2*)&sA[0][r * NF + pos] = pack4(tA[j]);
    }
    #pragma unroll
    for (int j = 0; j < BJ; ++j) {
        const int r = row00 + 16 * j;
        const int pos = (((f4 >> 1) ^ (r & 7)) << 3) + ((f4 & 1) << 2);
        *(u32x2*)&sB[0][r * NF + pos] = pack4(tB[j]);
    }
    #pragma unroll
    for (int j = 0; j < AJ; ++j) { async_load4(tA[j], pa[j]); pa[j] += NF; }
    #pragma unroll
    for (int j = 0; j < BJ; ++j) { async_load4(tB[j], pb[j]); pb[j] += NF; }

    __syncthreads();   // buf0 visible; e1 loads remain in flight

    const float inv_s = 32.0f / 12.0f;       // |1/sigma|
    const int sw = n & 7;
    const int aRow = (tl0 * 32 + n) * NF;    // second L-tile at +64*NF
    const int bRow = (tr * 32 + n) * NF;

    float sum = 0.0f;

    #pragma unroll
    for (int ep = 0; ep < EPB; ++ep) {
        const int cur = ep & 1;
        const int nxt = cur ^ 1;

        // -- compute on buf[cur]: pure LDS + VALU + MFMA, no vmem waits --
        f32x16 acc0 = {0,0,0,0,0,0,0,0,0,0,0,0,0,0,0,0};
        f32x16 acc1 = acc0;
        #pragma unroll
        for (int kc = 0; kc < 4; ++kc) {
            const int off = (((kc * 2 + h) ^ sw) << 3);
            const s16x8 a0 = *(const s16x8*)&sA[cur][aRow + off];
            const s16x8 a1 = *(const s16x8*)&sA[cur][aRow + 64 * NF + off];
            const s16x8 bf = *(const s16x8*)&sB[cur][bRow + off];
            acc0 = __builtin_amdgcn_mfma_f32_32x32x16_bf16(a0, bf, acc0, 0, 0, 0);
            acc1 = __builtin_amdgcn_mfma_f32_32x32x16_bf16(a1, bf, acc1, 0, 0, 0);
        }
        const float nmu = -(float)(e0 + ep) * (32.0f / 31.0f);  // mu_e/|s|
        #pragma unroll
        for (int i = 0; i < 16; ++i) {
            float z;
            z = __builtin_fmaf(d[0][i], inv_s, nmu); sum += __expf(-z * z) * acc0[i];
            z = __builtin_fmaf(d[1][i], inv_s, nmu); sum += __expf(-z * z) * acc1[i];
        }

        if (ep + 1 < EPB) {
            // -- wait e_{ep+1} (issued a full compute phase ago) --
            asm volatile("s_waitcnt vmcnt(0)" : TIE :: "memory");
            // -- convert + write e_{ep+1} into buf[nxt] --
            #pragma unroll
            for (int j = 0; j < AJ; ++j) {
                const int r = row00 + 16 * j;
                const int pos = (((f4 >> 1) ^ (r & 7)) << 3) + ((f4 & 1) << 2);
                *(u32x2*)&sA[nxt][r * NF + pos] = pack4(tA[j]);
            }
            #pragma unroll
            for (int j = 0; j < BJ; ++j) {
                const int r = row00 + 16 * j;
                const int pos = (((f4 >> 1) ^ (r & 7)) << 3) + ((f4 & 1) << 2);
                *(u32x2*)&sB[nxt][r * NF + pos] = pack4(tB[j]);
            }
            // -- issue e_{ep+2}; these cross the barrier below --
            if (ep + 2 < EPB) {
                #pragma unroll
                for (int j = 0; j < AJ; ++j) { async_load4(tA[j], pa[j]); pa[j] += NF; }
                #pragma unroll
                for (int j = 0; j < BJ; ++j) { async_load4(tB[j], pb[j]); pb[j] += NF; }
            }
            __syncthreads();   // lgkm drain for ds_writes; asm loads stay in flight
        }
    }

    // ---- reduce: wave -> block -> global atomic ----
    sum *= 0.01f;   // ENERGY_SCALE
    #pragma unroll
    for (int off = 32; off > 0; off >>= 1)
        sum += __shfl_down(sum, off, 64);
    if (lane == 0) sRed[wv] = sum;
    __syncthreads();
    if (t == 0) {
        float s = 0.f;
        #pragma unroll
        for (int w = 0; w < NWAVES; ++w) s += sRed[w];
        atomicAdd(&out[b], s);
    }
}

extern "C" void kernel_launch(void* const* d_in, const int* in_sizes, int n_in,
                              void* d_out, int out_size, void* d_ws, size_t ws_size,
                              hipStream_t stream) {
    const float* lig_feat  = (const float*)d_in[0];
    const float* rec_feat  = (const float*)d_in[1];
    const float* lig_coord = (const float*)d_in[2];
    const float* rec_coord = (const float*)d_in[3];
    float* out = (float*)d_out;

    hipMemsetAsync(out, 0, (size_t)out_size * sizeof(float), stream);

    dim3 grid(NB * NRT * EH);   // 1024 blocks: (b, r-tile, e-group)
    ff_kernel<<<grid, NTHREADS, 0, stream>>>(lig_feat, rec_feat,
                                             lig_coord, rec_coord, out);
}

// Round 4
// 206.096 us; speedup vs baseline: 1.3766x; 1.3766x over previous
//
#include <hip/hip_runtime.h>

// B=8, L=128, R=2048, E=32, F=64
#define NB 8
#define NL 128
#define NR 2048
#define NE 32
#define NF 64
#define RT 64                 // r-rows per block
#define NRT (NR / RT)         // 32 r-tiles
#define EH 4                  // e-groups (blocks) per (b, rt)
#define EPB (NE / EH)         // 8 e's per block
#define NTHREADS 256
#define NWAVES (NTHREADS / 64)   // 4
#define AJ 8                  // A 16B-loads per thread per e (128 rows)
#define BJ 4                  // B 16B-loads per thread per e (64 rows)

typedef __attribute__((ext_vector_type(4)))  float f32x4;
typedef __attribute__((ext_vector_type(16))) float f32x16;
typedef __attribute__((ext_vector_type(8)))  short s16x8;
typedef __attribute__((ext_vector_type(2)))  unsigned int u32x2;

// (bf16(b) << 16) | bf16(a), round-half-up: +0x8000 then byte-select
__device__ __forceinline__ unsigned bf16pair(float a, float b) {
    union { float f; unsigned u; } ua, ub; ua.f = a; ub.f = b;
    return __builtin_amdgcn_perm(ub.u + 0x8000u, ua.u + 0x8000u, 0x07060302u);
}

__device__ __forceinline__ u32x2 pack4(f32x4 v) {
    u32x2 r;
    r.x = bf16pair(v.x, v.y);
    r.y = bf16pair(v.z, v.w);
    return r;
}

// SGPR-base + 32-bit voffset load: base is wave-uniform (SGPR pair), voff is a
// loop-invariant per-thread byte offset. Compiler cannot sink or track it.
__device__ __forceinline__ void async_load4s(f32x4& r, const float* base, unsigned voff) {
    asm volatile("global_load_dwordx4 %0, %1, %2"
                 : "=v"(r) : "v"(voff), "s"(base) : "memory");
}

// Tie the staging registers to a counted wait so dependent packs can't hoist.
#define TIE "+v"(tA[0]), "+v"(tA[1]), "+v"(tA[2]), "+v"(tA[3]), \
            "+v"(tA[4]), "+v"(tA[5]), "+v"(tA[6]), "+v"(tA[7]), \
            "+v"(tB[0]), "+v"(tB[1]), "+v"(tB[2]), "+v"(tB[3])

// No min-occupancy clause: LB(256,3) budgeted 256/3=85 arch VGPRs and spilled
// 116 MB of scratch (R3: VGPR_Count=84, WRITE_SIZE=116MB). Let LDS (50.5 KB ->
// 3 blocks/CU) and natural VGPR use (~150 -> 3 waves/SIMD) set occupancy.
__global__ __launch_bounds__(NTHREADS) void ff_kernel(
    const float* __restrict__ lig_feat,
    const float* __restrict__ rec_feat,
    const float* __restrict__ lig_coord,
    const float* __restrict__ rec_coord,
    float* __restrict__ out)
{
    // bf16 tiles; rows of 64 elems = 8 x 16B chunks, chunk XOR-swizzled by (row&7)
    __shared__ __align__(16) unsigned short sA[2][NL * NF];  // 2 x 16 KB
    __shared__ __align__(16) unsigned short sB[2][RT * NF];  // 2 x 8 KB
    __shared__ float sLc[3][NL];
    __shared__ float sRc[3][RT];
    __shared__ float sRed[NWAVES];

    const int blk = blockIdx.x;
    const int eh  = blk & (EH - 1);
    const int rt  = (blk >> 2) & (NRT - 1);
    const int b   = blk >> 7;            // 8*32*4 = 1024 blocks
    const int e0  = eh * EPB;
    const int r0  = rt * RT;
    const int t   = threadIdx.x;
    const int lane = t & 63;
    const int wv   = t >> 6;

    // per-thread load pattern: f4 = 16B column (const), rows row00 + 16*j
    const int f4    = t & 15;
    const int row00 = t >> 4;            // 0..15

    // ---- coords to LDS (compiler-tracked vmem, drained before asm loads) ----
    for (int i = t; i < 3 * NL; i += NTHREADS) {
        const int c = i >> 7, l = i & 127;
        sLc[c][l] = lig_coord[((long)b * NL + l) * 3 + c];
    }
    for (int i = t; i < 3 * RT; i += NTHREADS) {
        const int c = i >> 6, r = i & 63;
        sRc[c][r] = rec_coord[((long)b * NR + r0 + r) * 3 + c];
    }

    // ---- loop-invariant 32-bit byte voffsets (e lives in the SGPR base) ----
    unsigned oa[AJ], ob[BJ];
    #pragma unroll
    for (int j = 0; j < AJ; ++j)
        oa[j] = (unsigned)((((b * NL + (row00 + 16 * j)) * NE) * NF + f4 * 4) * 4);
    #pragma unroll
    for (int j = 0; j < BJ; ++j)
        ob[j] = (unsigned)((((b * NR + r0 + (row00 + 16 * j)) * NE) * NF + f4 * 4) * 4);

    // uniform scalar bases; advance by NF floats per e (SALU only)
    const float* baseA = lig_feat + (size_t)e0 * NF;
    const float* baseB = rec_feat + (size_t)e0 * NF;

    f32x4 tA[AJ], tB[BJ];

    // issue e0 (12 loads in flight across the distance phase)
    #pragma unroll
    for (int j = 0; j < AJ; ++j) async_load4s(tA[j], baseA, oa[j]);
    #pragma unroll
    for (int j = 0; j < BJ; ++j) async_load4s(tB[j], baseB, ob[j]);
    baseA += NF; baseB += NF;

    __syncthreads();   // coords visible (lgkm drain only; asm loads stay in flight)

    // ---- distances once, kept in registers (2 L-tiles: tl0, tl0+2) ----
    const int n  = lane & 31;
    const int h  = lane >> 5;
    const int tr  = wv & 1;              // 0..1 over RT/32
    const int tl0 = wv >> 1;             // 0..1; L-tiles tl0 and tl0+2
    const int colr = tr * 32 + n;
    const float rx = sRc[0][colr], ry = sRc[1][colr], rz = sRc[2][colr];
    float d[2][16];
    #pragma unroll
    for (int t2 = 0; t2 < 2; ++t2) {
        const int tl = tl0 + 2 * t2;
        #pragma unroll
        for (int i = 0; i < 16; ++i) {
            const int row = tl * 32 + 4 * h + (i & 3) + ((i >> 2) << 3);
            const float dx = sLc[0][row] - rx;
            const float dy = sLc[1][row] - ry;
            const float dz = sLc[2][row] - rz;
            d[t2][i] = sqrtf(dx * dx + dy * dy + dz * dz);
        }
    }

    // ---- wait e0 -> pack to buf0; issue e1; barrier ----
    asm volatile("s_waitcnt vmcnt(0)" : TIE :: "memory");
    #pragma unroll
    for (int j = 0; j < AJ; ++j) {
        const int r = row00 + 16 * j;
        const int pos = (((f4 >> 1) ^ (r & 7)) << 3) + ((f4 & 1) << 2);
        *(u32x2*)&sA[0][r * NF + pos] = pack4(tA[j]);
    }
    #pragma unroll
    for (int j = 0; j < BJ; ++j) {
        const int r = row00 + 16 * j;
        const int pos = (((f4 >> 1) ^ (r & 7)) << 3) + ((f4 & 1) << 2);
        *(u32x2*)&sB[0][r * NF + pos] = pack4(tB[j]);
    }
    #pragma unroll
    for (int j = 0; j < AJ; ++j) async_load4s(tA[j], baseA, oa[j]);
    #pragma unroll
    for (int j = 0; j < BJ; ++j) async_load4s(tB[j], baseB, ob[j]);
    baseA += NF; baseB += NF;

    __syncthreads();   // buf0 visible; e1 loads remain in flight

    const float inv_s = 32.0f / 12.0f;       // |1/sigma|
    const int sw = n & 7;
    const int aRow = (tl0 * 32 + n) * NF;    // second L-tile at +64*NF
    const int bRow = (tr * 32 + n) * NF;

    float sum = 0.0f;

    #pragma unroll
    for (int ep = 0; ep < EPB; ++ep) {
        const int cur = ep & 1;
        const int nxt = cur ^ 1;

        // -- compute on buf[cur]: pure LDS + VALU + MFMA, no vmem waits --
        f32x16 acc0 = {0,0,0,0,0,0,0,0,0,0,0,0,0,0,0,0};
        f32x16 acc1 = acc0;
        #pragma unroll
        for (int kc = 0; kc < 4; ++kc) {
            const int off = (((kc * 2 + h) ^ sw) << 3);
            const s16x8 a0 = *(const s16x8*)&sA[cur][aRow + off];
            const s16x8 a1 = *(const s16x8*)&sA[cur][aRow + 64 * NF + off];
            const s16x8 bf = *(const s16x8*)&sB[cur][bRow + off];
            acc0 = __builtin_amdgcn_mfma_f32_32x32x16_bf16(a0, bf, acc0, 0, 0, 0);
            acc1 = __builtin_amdgcn_mfma_f32_32x32x16_bf16(a1, bf, acc1, 0, 0, 0);
        }
        const float nmu = -(float)(e0 + ep) * (32.0f / 31.0f);  // mu_e/|s|
        #pragma unroll
        for (int i = 0; i < 16; ++i) {
            float z;
            z = __builtin_fmaf(d[0][i], inv_s, nmu); sum += __expf(-z * z) * acc0[i];
            z = __builtin_fmaf(d[1][i], inv_s, nmu); sum += __expf(-z * z) * acc1[i];
        }

        if (ep + 1 < EPB) {
            // -- wait e_{ep+1} (issued a full compute phase ago) --
            asm volatile("s_waitcnt vmcnt(0)" : TIE :: "memory");
            // -- convert + write e_{ep+1} into buf[nxt] --
            #pragma unroll
            for (int j = 0; j < AJ; ++j) {
                const int r = row00 + 16 * j;
                const int pos = (((f4 >> 1) ^ (r & 7)) << 3) + ((f4 & 1) << 2);
                *(u32x2*)&sA[nxt][r * NF + pos] = pack4(tA[j]);
            }
            #pragma unroll
            for (int j = 0; j < BJ; ++j) {
                const int r = row00 + 16 * j;
                const int pos = (((f4 >> 1) ^ (r & 7)) << 3) + ((f4 & 1) << 2);
                *(u32x2*)&sB[nxt][r * NF + pos] = pack4(tB[j]);
            }
            // -- issue e_{ep+2}; these cross the barrier below --
            if (ep + 2 < EPB) {
                #pragma unroll
                for (int j = 0; j < AJ; ++j) async_load4s(tA[j], baseA, oa[j]);
                #pragma unroll
                for (int j = 0; j < BJ; ++j) async_load4s(tB[j], baseB, ob[j]);
                baseA += NF; baseB += NF;
            }
            __syncthreads();   // lgkm drain for ds_writes; asm loads stay in flight
        }
    }

    // ---- reduce: wave -> block -> global atomic ----
    sum *= 0.01f;   // ENERGY_SCALE
    #pragma unroll
    for (int off = 32; off > 0; off >>= 1)
        sum += __shfl_down(sum, off, 64);
    if (lane == 0) sRed[wv] = sum;
    __syncthreads();
    if (t == 0) {
        float s = 0.f;
        #pragma unroll
        for (int w = 0; w < NWAVES; ++w) s += sRed[w];
        atomicAdd(&out[b], s);
    }
}

extern "C" void kernel_launch(void* const* d_in, const int* in_sizes, int n_in,
                              void* d_out, int out_size, void* d_ws, size_t ws_size,
                              hipStream_t stream) {
    const float* lig_feat  = (const float*)d_in[0];
    const float* rec_feat  = (const float*)d_in[1];
    const float* lig_coord = (const float*)d_in[2];
    const float* rec_coord = (const float*)d_in[3];
    float* out = (float*)d_out;

    hipMemsetAsync(out, 0, (size_t)out_size * sizeof(float), stream);

    dim3 grid(NB * NRT * EH);   // 1024 blocks: (b, r-tile, e-group)
    ff_kernel<<<grid, NTHREADS, 0, stream>>>(lig_feat, rec_feat,
                                             lig_coord, rec_coord, out);
}